// Round 1
// 115.524 us; speedup vs baseline: 1.2028x; 1.2028x over previous
//
#include <hip/hip_runtime.h>

// B,C,H,W = 4,64,64,64 ; N = 4096 ; d = 8
#define BB 4
#define CC 64
#define NN 4096

typedef __attribute__((ext_vector_type(8))) short short8;
typedef __attribute__((ext_vector_type(4))) float f32x4;
typedef __attribute__((ext_vector_type(4))) unsigned uint4v;

__device__ inline ushort f2bf(float x) {                 // RNE float->bf16
    unsigned u = __float_as_uint(x);
    return (ushort)((u + 0x7fff + ((u >> 16) & 1)) >> 16);
}
__device__ inline float bf2f(ushort h) { return __uint_as_float(((unsigned)h) << 16); }

__device__ inline unsigned cvt_pk_bf16(float a, float b) {   // lo=bf16(a), hi=bf16(b)
    unsigned r;
    asm("v_cvt_pk_bf16_f32 %0, %1, %2" : "=v"(r) : "v"(a), "v"(b));
    return r;
}

// ws layout (ushort):
//   qTp [B][N][32] : q0..q7, q0h,q1h,q0l,q1l, 0*20                     (1 MB)
//   kTp [B][N][32] : k0..k7, col,row,col,row, 0*20                     (1 MB)
//   vsw [B][64 tiles][2 sb][4 g][64 lanes][8 jj]                       (2 MB)
//     KEY-PERMUTED B-frag: physical key j (kg=j>>4, qd=(j>>2)&3, r=j&3) is
//     stored at (sb=kg>>1, lane=qd*16+(e&15), jj=((kg&1)<<2)|r) so that the
//     PV A-operand is exactly the lane-local cvt_pk output of the S-MFMA
//     (col s*32+qd*8+jj holds key (2s+(jj>>2))*16+qd*4+(jj&3)). No LDS P.

// ---------------------------------------------------------------------------
// Kernel 1: QKV projection.
//   blocks 0..63   : q/k per pixel (rel-pos fold + hi/lo split, 32-half rows)
//   blocks 64..2111: v, 2 channels/thread (e, e+32), 64 pixels/wave,
//                    writes key-permuted bf16 vsw. 8192 v-waves hide latency.
// ---------------------------------------------------------------------------
__global__ __launch_bounds__(256) void qkv_kernel(
    const float* __restrict__ x,
    const float* __restrict__ Wq, const float* __restrict__ bq,
    const float* __restrict__ Wk, const float* __restrict__ bk,
    const float* __restrict__ Wv, const float* __restrict__ bv,
    ushort* __restrict__ qTp, ushort* __restrict__ kTp, ushort* __restrict__ vsw)
{
    const int blk = blockIdx.x;
    const int tid = threadIdx.x;

    if (blk < 64) {   // ---------------- q/k path ----------------
        const int idx = blk * 256 + tid;
        const int b = idx >> 12, n = idx & (NN - 1);
        const float* xb = x + (size_t)b * CC * NN + n;
        float sq[8], sk[8];
#pragma unroll
        for (int d = 0; d < 8; ++d) { sq[d] = bq[d]; sk[d] = bk[d]; }
#pragma unroll 8
        for (int c = 0; c < CC; ++c) {
            const float xc = xb[c * NN];
#pragma unroll
            for (int d = 0; d < 8; ++d) {
                sq[d] += Wq[d * CC + c] * xc;
                sk[d] += Wk[d * CC + c] * xc;
            }
        }
        ushort hq[32], hk[32];
#pragma unroll
        for (int i = 0; i < 32; ++i) { hq[i] = 0; hk[i] = 0; }
#pragma unroll
        for (int d = 0; d < 8; ++d) { hq[d] = f2bf(sq[d]); hk[d] = f2bf(sk[d]); }
        hq[8]  = hq[0];                               // q0 hi
        hq[9]  = hq[1];                               // q1 hi
        hq[10] = f2bf(sq[0] - bf2f(hq[0]));           // q0 lo
        hq[11] = f2bf(sq[1] - bf2f(hq[1]));           // q1 lo
        const float col = (float)(n & 63), row = (float)(n >> 6);
        hk[8] = f2bf(col); hk[9] = f2bf(row); hk[10] = hk[8]; hk[11] = hk[9];

        uint4* dq = (uint4*)(qTp + (size_t)(b * NN + n) * 32);
        uint4* dk = (uint4*)(kTp + (size_t)(b * NN + n) * 32);
        const uint4* s4q = (const uint4*)hq;
        const uint4* s4k = (const uint4*)hk;
#pragma unroll
        for (int i = 0; i < 4; ++i) { dq[i] = s4q[i]; dk[i] = s4k[i]; }
        return;
    }

    // ---------------- v path ----------------
    const int w2 = blk - 64;
    const int pix = w2 >> 3, ec = w2 & 7;
    const int wvid = tid >> 6, lane = tid & 63;
    const int eu = __builtin_amdgcn_readfirstlane(ec * 4 + wvid);   // 0..31
    const int idx = pix * 64 + lane;
    const int b = idx >> 12, n = idx & (NN - 1);
    const float* xb = x + (size_t)b * CC * NN + n;
    float s0 = bv[eu], s1 = bv[eu + 32];
#pragma unroll 8
    for (int c = 0; c < CC; ++c) {
        const float xc = xb[c * NN];
        s0 += Wv[eu * CC + c] * xc;
        s1 += Wv[(eu + 32) * CC + c] * xc;
    }
    const int j = n & 63, t = n >> 6;
    const int kg = j >> 4, qd = (j >> 2) & 3, r = j & 3;
    const int sb = kg >> 1, jj = ((kg & 1) << 2) | r;
    const size_t tb = (size_t)(b * 64 + t) * 4096;
    const int e2 = eu + 32;
    vsw[tb + (size_t)(((sb * 4 + (eu >> 4)) * 64 + qd * 16 + (eu & 15)) * 8 + jj)] = f2bf(s0);
    vsw[tb + (size_t)(((sb * 4 + (e2 >> 4)) * 64 + qd * 16 + (e2 & 15)) * 8 + jj)] = f2bf(s1);
}

// ---------------------------------------------------------------------------
// Kernel 2: MFMA attention. 512 blocks x 512 threads (8 waves), 32 queries
// per block (2 q-tiles), keys split 8-way (8 tiles/wave). XCD swizzle pins
// one batch image per XCD (1 MB working set < 4 MB L2).
// Pass A: exact max via S^T = K'.Q^T (C=0). Pass B: S with C=-M fused,
// exp -> cvt_pk bf16 -> PV A-frag is lane-local (key-permuted vsw), VALU
// denominator. No LDS in the main loop at all.
// ---------------------------------------------------------------------------
__global__ __launch_bounds__(512, 4) void attn_kernel(
    const ushort* __restrict__ qTp, const ushort* __restrict__ kTp,
    const ushort* __restrict__ vsw, float* __restrict__ out)
{
    const int blk = blockIdx.x;
    const int xcd = blk & 7, i8 = blk >> 3;
    const int b  = xcd >> 1;                          // one b per XCD pair-slot
    const int nq = (((xcd & 1) << 6) | i8) << 5;      // 32-query base
    const int tid = threadIdx.x;
    const int wv = tid >> 6, lane = tid & 63;
    const int nn = lane & 15, quad = lane >> 4;

    __shared__ float Cb[8][1024];   // per-wave C-layout partials (one q-tile)
    __shared__ float Mx[8][32];
    __shared__ float Db[8][32];
    __shared__ float dn[32];

    // Q B-frags: lane holds q-channels quad*8..+8 of queries nq+nn, nq+16+nn
    const short8 qf0 = *(const short8*)(qTp + ((size_t)(b * NN + nq + nn) * 32 + quad * 8));
    const short8 qf1 = *(const short8*)(qTp + ((size_t)(b * NN + nq + 16 + nn) * 32 + quad * 8));
    const ushort* kb = kTp + (size_t)b * NN * 32;

    // ---------------- Pass A: exact max ----------------
    float Ml0 = -1e30f, Ml1 = -1e30f;
    for (int t8 = 0; t8 < 8; ++t8) {
        const int t = wv * 8 + t8;
#pragma unroll
        for (int kg = 0; kg < 4; ++kg) {
            const short8 kf = *(const short8*)(kb + ((size_t)(t * 64 + kg * 16 + nn) * 32 + quad * 8));
            const f32x4 S0 = __builtin_amdgcn_mfma_f32_16x16x32_bf16(kf, qf0, (f32x4){0.f,0.f,0.f,0.f}, 0, 0, 0);
            const f32x4 S1 = __builtin_amdgcn_mfma_f32_16x16x32_bf16(kf, qf1, (f32x4){0.f,0.f,0.f,0.f}, 0, 0, 0);
            Ml0 = fmaxf(Ml0, fmaxf(fmaxf(S0[0], S0[1]), fmaxf(S0[2], S0[3])));
            Ml1 = fmaxf(Ml1, fmaxf(fmaxf(S1[0], S1[1]), fmaxf(S1[2], S1[3])));
        }
    }
    Ml0 = fmaxf(Ml0, __shfl_xor(Ml0, 16, 64));
    Ml0 = fmaxf(Ml0, __shfl_xor(Ml0, 32, 64));
    Ml1 = fmaxf(Ml1, __shfl_xor(Ml1, 16, 64));
    Ml1 = fmaxf(Ml1, __shfl_xor(Ml1, 32, 64));
    if (quad == 0) { Mx[wv][nn] = Ml0; Mx[wv][16 + nn] = Ml1; }
    __syncthreads();
    float M0 = Mx[0][nn], M1 = Mx[0][16 + nn];
#pragma unroll
    for (int w = 1; w < 8; ++w) { M0 = fmaxf(M0, Mx[w][nn]); M1 = fmaxf(M1, Mx[w][16 + nn]); }
    const f32x4 nM0 = {-M0, -M0, -M0, -M0};
    const f32x4 nM1 = {-M1, -M1, -M1, -M1};

    // ---------------- Pass B: exp + PV, all in registers ----------------
    f32x4 acc0[4], acc1[4];
#pragma unroll
    for (int g = 0; g < 4; ++g) {
        acc0[g] = (f32x4){0.f,0.f,0.f,0.f};
        acc1[g] = (f32x4){0.f,0.f,0.f,0.f};
    }
    float dl0 = 0.f, dl1 = 0.f;

    for (int t8 = 0; t8 < 8; ++t8) {
        const int t = wv * 8 + t8;
        unsigned pw0[8], pw1[8];
#pragma unroll
        for (int kg = 0; kg < 4; ++kg) {
            const short8 kf = *(const short8*)(kb + ((size_t)(t * 64 + kg * 16 + nn) * 32 + quad * 8));
            const f32x4 S0 = __builtin_amdgcn_mfma_f32_16x16x32_bf16(kf, qf0, nM0, 0, 0, 0); // S - M fused
            const f32x4 S1 = __builtin_amdgcn_mfma_f32_16x16x32_bf16(kf, qf1, nM1, 0, 0, 0);
            const float w00 = __expf(S0[0]), w01 = __expf(S0[1]);
            const float w02 = __expf(S0[2]), w03 = __expf(S0[3]);
            const float w10 = __expf(S1[0]), w11 = __expf(S1[1]);
            const float w12 = __expf(S1[2]), w13 = __expf(S1[3]);
            dl0 += (w00 + w01) + (w02 + w03);
            dl1 += (w10 + w11) + (w12 + w13);
            pw0[2 * kg]     = cvt_pk_bf16(w00, w01);
            pw0[2 * kg + 1] = cvt_pk_bf16(w02, w03);
            pw1[2 * kg]     = cvt_pk_bf16(w10, w11);
            pw1[2 * kg + 1] = cvt_pk_bf16(w12, w13);
        }
        // A-frags are lane-local thanks to the key-permuted vsw layout
        const uint4v u00 = {pw0[0], pw0[1], pw0[2], pw0[3]};
        const uint4v u01 = {pw0[4], pw0[5], pw0[6], pw0[7]};
        const uint4v u10 = {pw1[0], pw1[1], pw1[2], pw1[3]};
        const uint4v u11 = {pw1[4], pw1[5], pw1[6], pw1[7]};
        const short8 a00 = __builtin_bit_cast(short8, u00);
        const short8 a01 = __builtin_bit_cast(short8, u01);
        const short8 a10 = __builtin_bit_cast(short8, u10);
        const short8 a11 = __builtin_bit_cast(short8, u11);

        const ushort* vb = vsw + (size_t)(b * 64 + t) * 4096;
#pragma unroll
        for (int g = 0; g < 4; ++g) {
            const short8 vf = *(const short8*)(vb + g * 512 + lane * 8);
            acc0[g] = __builtin_amdgcn_mfma_f32_16x16x32_bf16(a00, vf, acc0[g], 0, 0, 0);
            acc1[g] = __builtin_amdgcn_mfma_f32_16x16x32_bf16(a10, vf, acc1[g], 0, 0, 0);
        }
#pragma unroll
        for (int g = 0; g < 4; ++g) {
            const short8 vf = *(const short8*)(vb + 2048 + g * 512 + lane * 8);
            acc0[g] = __builtin_amdgcn_mfma_f32_16x16x32_bf16(a01, vf, acc0[g], 0, 0, 0);
            acc1[g] = __builtin_amdgcn_mfma_f32_16x16x32_bf16(a11, vf, acc1[g], 0, 0, 0);
        }
    }

    // ---------------- denominators + cross-wave combine ----------------
    dl0 += __shfl_xor(dl0, 16, 64); dl0 += __shfl_xor(dl0, 32, 64);
    dl1 += __shfl_xor(dl1, 16, 64); dl1 += __shfl_xor(dl1, 32, 64);
    if (quad == 0) { Db[wv][nn] = dl0; Db[wv][16 + nn] = dl1; }

#pragma unroll
    for (int g = 0; g < 4; ++g)
#pragma unroll
        for (int rr = 0; rr < 4; ++rr)
            Cb[wv][(g * 4 + rr) * 64 + lane] = acc0[g][rr];
    __syncthreads();

    if (tid < 32) {
        float s = Db[0][tid];
#pragma unroll
        for (int w = 1; w < 8; ++w) s += Db[w][tid];
        dn[tid] = s;
    }
    __syncthreads();

    // stage 0: queries nq..nq+15
#pragma unroll
    for (int it = 0; it < 2; ++it) {
        const int e = tid + it * 512;
        const int q = e & 15, c = e >> 4;
        const int src = ((c >> 4) * 4 + (q & 3)) * 64 + (q >> 2) * 16 + (c & 15);
        float v = Cb[0][src];
#pragma unroll
        for (int w = 1; w < 8; ++w) v += Cb[w][src];
        out[(size_t)(b * CC + c) * NN + nq + q] = v / dn[q];
    }
    __syncthreads();

#pragma unroll
    for (int g = 0; g < 4; ++g)
#pragma unroll
        for (int rr = 0; rr < 4; ++rr)
            Cb[wv][(g * 4 + rr) * 64 + lane] = acc1[g][rr];
    __syncthreads();

    // stage 1: queries nq+16..nq+31
#pragma unroll
    for (int it = 0; it < 2; ++it) {
        const int e = tid + it * 512;
        const int q = e & 15, c = e >> 4;
        const int src = ((c >> 4) * 4 + (q & 3)) * 64 + (q >> 2) * 16 + (c & 15);
        float v = Cb[0][src];
#pragma unroll
        for (int w = 1; w < 8; ++w) v += Cb[w][src];
        out[(size_t)(b * CC + c) * NN + nq + 16 + q] = v / dn[16 + q];
    }
}

extern "C" void kernel_launch(void* const* d_in, const int* in_sizes, int n_in,
                              void* d_out, int out_size, void* d_ws, size_t ws_size,
                              hipStream_t stream) {
    const float* x  = (const float*)d_in[0];
    const float* Wq = (const float*)d_in[1];
    const float* bq = (const float*)d_in[2];
    const float* Wk = (const float*)d_in[3];
    const float* bk = (const float*)d_in[4];
    const float* Wv = (const float*)d_in[5];
    const float* bv = (const float*)d_in[6];
    float* out = (float*)d_out;

    ushort* ws  = (ushort*)d_ws;
    ushort* qTp = ws;                                  // B*N*32 halves
    ushort* kTp = ws + (size_t)BB * NN * 32;           // B*N*32 halves
    ushort* vsw = ws + (size_t)2 * BB * NN * 32;       // B*64*4096 halves (2 MB)

    qkv_kernel<<<2112, 256, 0, stream>>>(x, Wq, bq, Wk, bk, Wv, bv, qTp, kTp, vsw);
    attn_kernel<<<512, 512, 0, stream>>>(qTp, kTp, vsw, out);
}

// Round 8
// 114.311 us; speedup vs baseline: 1.2156x; 1.0106x over previous
//
#include <hip/hip_runtime.h>

// B,C,H,W = 4,64,64,64 ; N = 4096 ; d = 8
#define BB 4
#define CC 64
#define NN 4096

typedef __attribute__((ext_vector_type(8))) short short8;
typedef __attribute__((ext_vector_type(4))) float f32x4;
typedef __attribute__((ext_vector_type(4))) unsigned uint4v;

__device__ inline ushort f2bf(float x) {                 // RNE float->bf16
    unsigned u = __float_as_uint(x);
    return (ushort)((u + 0x7fff + ((u >> 16) & 1)) >> 16);
}
__device__ inline float bf2f(ushort h) { return __uint_as_float(((unsigned)h) << 16); }

__device__ inline unsigned cvt_pk_bf16(float a, float b) {   // lo=bf16(a), hi=bf16(b)
    unsigned r;
    asm("v_cvt_pk_bf16_f32 %0, %1, %2" : "=v"(r) : "v"(a), "v"(b));
    return r;
}

// ws layout (ushort):
//   qTp [B][N][32] : q0..q7, q0h,q1h,q0l,q1l, 0*20                     (1 MB)
//   kTp [B][N][32] : k0..k7, col,row,col,row, 0*20                     (1 MB)
//   vsw [B][64 tiles][2 sb][4 g][64 lanes][8 jj]                       (2 MB)
//     KEY-PERMUTED B-frag: physical key j (kg=j>>4, qd=(j>>2)&3, r=j&3) is
//     stored at (sb=kg>>1, lane=qd*16+(e&15), jj=((kg&1)<<2)|r) so that the
//     PV A-operand is exactly the lane-local cvt_pk output of the S-MFMA
//     (col s*32+qd*8+jj holds key (2s+(jj>>2))*16+qd*4+(jj&3)). No LDS P.

// ---------------------------------------------------------------------------
// Kernel 1: QKV projection.
//   blocks 0..63   : q/k per pixel (rel-pos fold + hi/lo split, 32-half rows)
//   blocks 64..2111: v, 2 channels/thread (eu, eu+32), 64 pixels/wave,
//                    writes key-permuted bf16 vsw. 8192 v-waves hide latency.
// ---------------------------------------------------------------------------
__global__ __launch_bounds__(256) void qkv_kernel(
    const float* __restrict__ x,
    const float* __restrict__ Wq, const float* __restrict__ bq,
    const float* __restrict__ Wk, const float* __restrict__ bk,
    const float* __restrict__ Wv, const float* __restrict__ bv,
    ushort* __restrict__ qTp, ushort* __restrict__ kTp, ushort* __restrict__ vsw)
{
    const int blk = blockIdx.x;
    const int tid = threadIdx.x;

    if (blk < 64) {   // ---------------- q/k path ----------------
        const int idx = blk * 256 + tid;
        const int b = idx >> 12, n = idx & (NN - 1);
        const float* xb = x + (size_t)b * CC * NN + n;
        float sq[8], sk[8];
#pragma unroll
        for (int d = 0; d < 8; ++d) { sq[d] = bq[d]; sk[d] = bk[d]; }
#pragma unroll 8
        for (int c = 0; c < CC; ++c) {
            const float xc = xb[c * NN];
#pragma unroll
            for (int d = 0; d < 8; ++d) {
                sq[d] += Wq[d * CC + c] * xc;
                sk[d] += Wk[d * CC + c] * xc;
            }
        }
        ushort hq[32], hk[32];
#pragma unroll
        for (int i = 0; i < 32; ++i) { hq[i] = 0; hk[i] = 0; }
#pragma unroll
        for (int d = 0; d < 8; ++d) { hq[d] = f2bf(sq[d]); hk[d] = f2bf(sk[d]); }
        hq[8]  = hq[0];                               // q0 hi
        hq[9]  = hq[1];                               // q1 hi
        hq[10] = f2bf(sq[0] - bf2f(hq[0]));           // q0 lo
        hq[11] = f2bf(sq[1] - bf2f(hq[1]));           // q1 lo
        const float col = (float)(n & 63), row = (float)(n >> 6);
        hk[8] = f2bf(col); hk[9] = f2bf(row); hk[10] = hk[8]; hk[11] = hk[9];

        uint4* dq = (uint4*)(qTp + (size_t)(b * NN + n) * 32);
        uint4* dk = (uint4*)(kTp + (size_t)(b * NN + n) * 32);
        const uint4* s4q = (const uint4*)hq;
        const uint4* s4k = (const uint4*)hk;
#pragma unroll
        for (int i = 0; i < 4; ++i) { dq[i] = s4q[i]; dk[i] = s4k[i]; }
        return;
    }

    // ---------------- v path ----------------
    const int w2 = blk - 64;
    const int pix = w2 >> 3, ec = w2 & 7;
    const int wvid = tid >> 6, lane = tid & 63;
    const int eu = __builtin_amdgcn_readfirstlane(ec * 4 + wvid);   // 0..31
    const int idx = pix * 64 + lane;
    const int b = idx >> 12, n = idx & (NN - 1);
    const float* xb = x + (size_t)b * CC * NN + n;
    float s0 = bv[eu], s1 = bv[eu + 32];
#pragma unroll 8
    for (int c = 0; c < CC; ++c) {
        const float xc = xb[c * NN];
        s0 += Wv[eu * CC + c] * xc;
        s1 += Wv[(eu + 32) * CC + c] * xc;
    }
    const int j = n & 63, t = n >> 6;
    const int kg = j >> 4, qd = (j >> 2) & 3, r = j & 3;
    const int sb = kg >> 1, jj = ((kg & 1) << 2) | r;
    const size_t tb = (size_t)(b * 64 + t) * 4096;
    const int e2 = eu + 32;
    vsw[tb + (size_t)(((sb * 4 + (eu >> 4)) * 64 + qd * 16 + (eu & 15)) * 8 + jj)] = f2bf(s0);
    vsw[tb + (size_t)(((sb * 4 + (e2 >> 4)) * 64 + qd * 16 + (e2 & 15)) * 8 + jj)] = f2bf(s1);
}

// ---------------------------------------------------------------------------
// Kernel 2: MFMA attention. 512 blocks x 512 threads (8 waves), 32 queries
// per block (2 q-tiles), keys split 8-way (8 tiles/wave). XCD swizzle pins
// one batch image per XCD pair (<1 MB in L2).
// Pass A: exact max via S^T = K'.Q^T (C=0). Pass B: S with C=-M fused,
// exp -> cvt_pk bf16 -> PV A-frag is lane-local (key-permuted vsw), VALU
// denominator. No LDS in the main loop at all.
// ---------------------------------------------------------------------------
__global__ __launch_bounds__(512, 4) void attn_kernel(
    const ushort* __restrict__ qTp, const ushort* __restrict__ kTp,
    const ushort* __restrict__ vsw, float* __restrict__ out)
{
    const int blk = blockIdx.x;
    const int xcd = blk & 7, i8 = blk >> 3;
    const int b  = xcd >> 1;                          // one b per XCD pair-slot
    const int nq = (((xcd & 1) << 6) | i8) << 5;      // 32-query base
    const int tid = threadIdx.x;
    const int wv = tid >> 6, lane = tid & 63;
    const int nn = lane & 15, quad = lane >> 4;

    __shared__ float Cb[8][1024];   // per-wave C-layout partials (one q-tile)
    __shared__ float Mx[8][32];
    __shared__ float Db[8][32];
    __shared__ float dn[32];

    // Q B-frags: lane holds q-channels quad*8..+8 of queries nq+nn, nq+16+nn
    const short8 qf0 = *(const short8*)(qTp + ((size_t)(b * NN + nq + nn) * 32 + quad * 8));
    const short8 qf1 = *(const short8*)(qTp + ((size_t)(b * NN + nq + 16 + nn) * 32 + quad * 8));
    const ushort* kb = kTp + (size_t)b * NN * 32;

    // ---------------- Pass A: exact max ----------------
    float Ml0 = -1e30f, Ml1 = -1e30f;
    for (int t8 = 0; t8 < 8; ++t8) {
        const int t = wv * 8 + t8;
#pragma unroll
        for (int kg = 0; kg < 4; ++kg) {
            const short8 kf = *(const short8*)(kb + ((size_t)(t * 64 + kg * 16 + nn) * 32 + quad * 8));
            const f32x4 S0 = __builtin_amdgcn_mfma_f32_16x16x32_bf16(kf, qf0, (f32x4){0.f,0.f,0.f,0.f}, 0, 0, 0);
            const f32x4 S1 = __builtin_amdgcn_mfma_f32_16x16x32_bf16(kf, qf1, (f32x4){0.f,0.f,0.f,0.f}, 0, 0, 0);
            Ml0 = fmaxf(Ml0, fmaxf(fmaxf(S0[0], S0[1]), fmaxf(S0[2], S0[3])));
            Ml1 = fmaxf(Ml1, fmaxf(fmaxf(S1[0], S1[1]), fmaxf(S1[2], S1[3])));
        }
    }
    Ml0 = fmaxf(Ml0, __shfl_xor(Ml0, 16, 64));
    Ml0 = fmaxf(Ml0, __shfl_xor(Ml0, 32, 64));
    Ml1 = fmaxf(Ml1, __shfl_xor(Ml1, 16, 64));
    Ml1 = fmaxf(Ml1, __shfl_xor(Ml1, 32, 64));
    if (quad == 0) { Mx[wv][nn] = Ml0; Mx[wv][16 + nn] = Ml1; }
    __syncthreads();
    float M0 = Mx[0][nn], M1 = Mx[0][16 + nn];
#pragma unroll
    for (int w = 1; w < 8; ++w) { M0 = fmaxf(M0, Mx[w][nn]); M1 = fmaxf(M1, Mx[w][16 + nn]); }
    const f32x4 nM0 = {-M0, -M0, -M0, -M0};
    const f32x4 nM1 = {-M1, -M1, -M1, -M1};

    // ---------------- Pass B: exp + PV, all in registers ----------------
    f32x4 acc0[4], acc1[4];
#pragma unroll
    for (int g = 0; g < 4; ++g) {
        acc0[g] = (f32x4){0.f,0.f,0.f,0.f};
        acc1[g] = (f32x4){0.f,0.f,0.f,0.f};
    }
    float dl0 = 0.f, dl1 = 0.f;

    for (int t8 = 0; t8 < 8; ++t8) {
        const int t = wv * 8 + t8;
        unsigned pw0[8], pw1[8];
#pragma unroll
        for (int kg = 0; kg < 4; ++kg) {
            const short8 kf = *(const short8*)(kb + ((size_t)(t * 64 + kg * 16 + nn) * 32 + quad * 8));
            const f32x4 S0 = __builtin_amdgcn_mfma_f32_16x16x32_bf16(kf, qf0, nM0, 0, 0, 0); // S - M fused
            const f32x4 S1 = __builtin_amdgcn_mfma_f32_16x16x32_bf16(kf, qf1, nM1, 0, 0, 0);
            const float w00 = __expf(S0[0]), w01 = __expf(S0[1]);
            const float w02 = __expf(S0[2]), w03 = __expf(S0[3]);
            const float w10 = __expf(S1[0]), w11 = __expf(S1[1]);
            const float w12 = __expf(S1[2]), w13 = __expf(S1[3]);
            dl0 += (w00 + w01) + (w02 + w03);
            dl1 += (w10 + w11) + (w12 + w13);
            pw0[2 * kg]     = cvt_pk_bf16(w00, w01);
            pw0[2 * kg + 1] = cvt_pk_bf16(w02, w03);
            pw1[2 * kg]     = cvt_pk_bf16(w10, w11);
            pw1[2 * kg + 1] = cvt_pk_bf16(w12, w13);
        }
        // A-frags are lane-local thanks to the key-permuted vsw layout
        const uint4v u00 = {pw0[0], pw0[1], pw0[2], pw0[3]};
        const uint4v u01 = {pw0[4], pw0[5], pw0[6], pw0[7]};
        const uint4v u10 = {pw1[0], pw1[1], pw1[2], pw1[3]};
        const uint4v u11 = {pw1[4], pw1[5], pw1[6], pw1[7]};
        const short8 a00 = __builtin_bit_cast(short8, u00);
        const short8 a01 = __builtin_bit_cast(short8, u01);
        const short8 a10 = __builtin_bit_cast(short8, u10);
        const short8 a11 = __builtin_bit_cast(short8, u11);

        const ushort* vb = vsw + (size_t)(b * 64 + t) * 4096;
#pragma unroll
        for (int g = 0; g < 4; ++g) {
            const short8 vf = *(const short8*)(vb + g * 512 + lane * 8);
            acc0[g] = __builtin_amdgcn_mfma_f32_16x16x32_bf16(a00, vf, acc0[g], 0, 0, 0);
            acc1[g] = __builtin_amdgcn_mfma_f32_16x16x32_bf16(a10, vf, acc1[g], 0, 0, 0);
        }
#pragma unroll
        for (int g = 0; g < 4; ++g) {
            const short8 vf = *(const short8*)(vb + 2048 + g * 512 + lane * 8);
            acc0[g] = __builtin_amdgcn_mfma_f32_16x16x32_bf16(a01, vf, acc0[g], 0, 0, 0);
            acc1[g] = __builtin_amdgcn_mfma_f32_16x16x32_bf16(a11, vf, acc1[g], 0, 0, 0);
        }
    }

    // ---------------- denominators + cross-wave combine ----------------
    dl0 += __shfl_xor(dl0, 16, 64); dl0 += __shfl_xor(dl0, 32, 64);
    dl1 += __shfl_xor(dl1, 16, 64); dl1 += __shfl_xor(dl1, 32, 64);
    if (quad == 0) { Db[wv][nn] = dl0; Db[wv][16 + nn] = dl1; }

#pragma unroll
    for (int g = 0; g < 4; ++g)
#pragma unroll
        for (int r = 0; r < 4; ++r)
            Cb[wv][(g * 4 + r) * 64 + lane] = acc0[g][r];
    __syncthreads();

    if (tid < 32) {
        float s = Db[0][tid];
#pragma unroll
        for (int w = 1; w < 8; ++w) s += Db[w][tid];
        dn[tid] = s;
    }
    __syncthreads();

    // stage 0: queries nq..nq+15
#pragma unroll
    for (int it = 0; it < 2; ++it) {
        const int e = tid + it * 512;
        const int q = e & 15, c = e >> 4;
        const int src = ((c >> 4) * 4 + (q & 3)) * 64 + (q >> 2) * 16 + (c & 15);
        float v = Cb[0][src];
#pragma unroll
        for (int w = 1; w < 8; ++w) v += Cb[w][src];
        out[(size_t)(b * CC + c) * NN + nq + q] = v / dn[q];
    }
    __syncthreads();

#pragma unroll
    for (int g = 0; g < 4; ++g)
#pragma unroll
        for (int r = 0; r < 4; ++r)
            Cb[wv][(g * 4 + r) * 64 + lane] = acc1[g][r];
    __syncthreads();

    // stage 1: queries nq+16..nq+31
#pragma unroll
    for (int it = 0; it < 2; ++it) {
        const int e = tid + it * 512;
        const int q = e & 15, c = e >> 4;
        const int src = ((c >> 4) * 4 + (q & 3)) * 64 + (q >> 2) * 16 + (c & 15);
        float v = Cb[0][src];
#pragma unroll
        for (int w = 1; w < 8; ++w) v += Cb[w][src];
        out[(size_t)(b * CC + c) * NN + nq + 16 + q] = v / dn[16 + q];
    }
}

extern "C" void kernel_launch(void* const* d_in, const int* in_sizes, int n_in,
                              void* d_out, int out_size, void* d_ws, size_t ws_size,
                              hipStream_t stream) {
    const float* x  = (const float*)d_in[0];
    const float* Wq = (const float*)d_in[1];
    const float* bq = (const float*)d_in[2];
    const float* Wk = (const float*)d_in[3];
    const float* bk = (const float*)d_in[4];
    const float* Wv = (const float*)d_in[5];
    const float* bv = (const float*)d_in[6];
    float* out = (float*)d_out;

    ushort* ws  = (ushort*)d_ws;
    ushort* qTp = ws;                                  // B*N*32 halves
    ushort* kTp = ws + (size_t)BB * NN * 32;           // B*N*32 halves
    ushort* vsw = ws + (size_t)2 * BB * NN * 32;       // B*64*4096 halves (2 MB)

    qkv_kernel<<<2112, 256, 0, stream>>>(x, Wq, bq, Wk, bk, Wv, bv, qTp, kTp, vsw);
    attn_kernel<<<512, 512, 0, stream>>>(qTp, kTp, vsw, out);
}